// Round 3
// baseline (4476.283 us; speedup 1.0000x reference)
//
#include <hip/hip_runtime.h>
#include <hip/hip_bf16.h>

// ---------------------------------------------------------------------------
// Transformer encoder fwd: B=32, S=1024, D=768, L=4, H=1536, C=6
// bf16 MFMA GEMMs, fp32 residual. Output written as FLOAT32 (reference dtype).
// Workspace-adaptive: batches processed in groups of G (8.4 MiB scratch per
// batch); G picked at launch from ws_size. Fixed part ~134 MB.
// ---------------------------------------------------------------------------

typedef float f32x4 __attribute__((ext_vector_type(4)));
typedef unsigned short u16x4 __attribute__((ext_vector_type(4)));
typedef unsigned short u16x8 __attribute__((ext_vector_type(8)));
typedef __bf16 bf16x8 __attribute__((ext_vector_type(8)));

#define NB  32
#define NS  1024
#define ND  768
#define NH  1536
#define NL  4
#define NM  (NB * NS)   // 32768 rows total

__device__ __forceinline__ unsigned short f2bf(float f) {
    unsigned u = __builtin_bit_cast(unsigned, f);
    unsigned r = (u + 0x7FFFu + ((u >> 16) & 1u)) >> 16;   // RNE
    return (unsigned short)r;
}
__device__ __forceinline__ float bf2f(unsigned short h) {
    return __builtin_bit_cast(float, (unsigned)h << 16);
}

__device__ __forceinline__ void gl_lds16(const void* g, void* l) {
    __builtin_amdgcn_global_load_lds(
        (const __attribute__((address_space(1))) unsigned int*)g,
        (__attribute__((address_space(3))) unsigned int*)l, 16, 0, 0);
}

// ---------------- embedding ------------------------------------------------
__global__ void embed_kernel(const int* __restrict__ tok,
                             const float* __restrict__ emb,
                             const float* __restrict__ pos,
                             float* __restrict__ x) {
    const int row = blockIdx.x;
    const int c = threadIdx.x;                 // 192 threads, one float4 each
    const int tk = tok[row];
    const int s = row & (NS - 1);
    f32x4 e = *(const f32x4*)(emb + (size_t)tk * ND + c * 4);
    f32x4 p = *(const f32x4*)(pos + (size_t)s * ND + c * 4);
    f32x4 r = e + p;
    *(f32x4*)(x + (size_t)row * ND + c * 4) = r;
}

// ---------------- key-padding mask bias ------------------------------------
__global__ void mask_kernel(const int* __restrict__ tok, float* __restrict__ mb) {
    const int i = blockIdx.x * 256 + threadIdx.x;
    mb[i] = (tok[i] == 0) ? -__builtin_inff() : 0.0f;
}

// ---------------- weight fp32 [R][C] -> bf16 transposed [C][R] --------------
__global__ __launch_bounds__(256)
void wt_kernel(const float* __restrict__ in, unsigned short* __restrict__ out,
               int R, int Cc) {
    __shared__ float ls[64][65];
    const int t = threadIdx.x;
    const size_t z = (size_t)blockIdx.z * R * Cc;
    const int r0 = blockIdx.y * 64, c0 = blockIdx.x * 64;
    #pragma unroll
    for (int i = 0; i < 4; i++) {
        const int r = i * 16 + (t >> 4);
        const int c = (t & 15) * 4;
        f32x4 v = *(const f32x4*)(in + z + (size_t)(r0 + r) * Cc + c0 + c);
        ls[r][c] = v[0]; ls[r][c + 1] = v[1]; ls[r][c + 2] = v[2]; ls[r][c + 3] = v[3];
    }
    __syncthreads();
    #pragma unroll
    for (int i = 0; i < 2; i++) {
        const int c = i * 32 + (t >> 3);
        const int r = (t & 7) * 8;
        u16x8 o;
        #pragma unroll
        for (int j = 0; j < 8; j++) o[j] = f2bf(ls[r + j][c]);
        *(u16x8*)(out + z + (size_t)(c0 + c) * R + r0 + r) = o;
    }
}

// ---------------- batched bf16 transpose: V[b][s][d] -> Vt[b][d][s] ---------
__global__ __launch_bounds__(256)
void tv_kernel(const unsigned short* __restrict__ v, unsigned short* __restrict__ vt) {
    __shared__ unsigned short ls[64][80];
    const int t = threadIdx.x;
    const int b = blockIdx.z;
    const int s0 = blockIdx.x * 64, d0 = blockIdx.y * 64;
    const unsigned short* vb = v + (size_t)b * NS * ND;
    unsigned short* vtb = vt + (size_t)b * ND * NS;
    #pragma unroll
    for (int i = 0; i < 2; i++) {
        const int sr = i * 32 + (t >> 3);
        const int dc = (t & 7) * 8;
        *(u16x8*)(&ls[sr][dc]) = *(const u16x8*)(vb + (size_t)(s0 + sr) * ND + d0 + dc);
    }
    __syncthreads();
    #pragma unroll
    for (int i = 0; i < 2; i++) {
        const int dr = i * 32 + (t >> 3);
        const int sc = (t & 7) * 8;
        u16x8 o;
        #pragma unroll
        for (int j = 0; j < 8; j++) o[j] = ls[sc + j][dr];
        *(u16x8*)(vtb + (size_t)(d0 + dr) * NS + s0 + sc) = o;
    }
}

// ---------------- LayerNorm fp32 in -> bf16 out, one wave per row -----------
__global__ __launch_bounds__(256)
void ln_kernel(const float* __restrict__ x, const float* __restrict__ g,
               const float* __restrict__ bta, unsigned short* __restrict__ out) {
    const int row = blockIdx.x * 4 + (threadIdx.x >> 6);
    const int l = threadIdx.x & 63;
    const float* xr = x + (size_t)row * ND;
    f32x4 vv[3];
    float s = 0.f, ss = 0.f;
    #pragma unroll
    for (int j = 0; j < 3; j++) {
        vv[j] = *(const f32x4*)(xr + (j * 64 + l) * 4);
        #pragma unroll
        for (int i = 0; i < 4; i++) { s += vv[j][i]; ss += vv[j][i] * vv[j][i]; }
    }
    #pragma unroll
    for (int off = 32; off >= 1; off >>= 1) {
        s += __shfl_xor(s, off); ss += __shfl_xor(ss, off);
    }
    const float mean = s * (1.0f / ND);
    const float var = ss * (1.0f / ND) - mean * mean;
    const float rstd = rsqrtf(var + 1e-5f);
    #pragma unroll
    for (int j = 0; j < 3; j++) {
        const int c = (j * 64 + l) * 4;
        f32x4 gv = *(const f32x4*)(g + c);
        f32x4 bv = *(const f32x4*)(bta + c);
        u16x4 o;
        #pragma unroll
        for (int i = 0; i < 4; i++) o[i] = f2bf((vv[j][i] - mean) * rstd * gv[i] + bv[i]);
        *(u16x4*)(out + (size_t)row * ND + c) = o;
    }
}

// ---------------- GEMM: C[M,N] = A[M,K](bf16) @ Bt[N,K](bf16)^T -------------
// 128x128 tile, BK=64, 4 waves, 16x16x32 MFMA, global_load_lds staging.
// EPI: 0 = scale+bias -> bf16; 1 = relu(bias+v) -> bf16; 2 = fp32 C += v
template<int EPI>
__global__ __launch_bounds__(256)
void gemm_kernel(const unsigned short* __restrict__ A,
                 const unsigned short* __restrict__ Bt,
                 const float* __restrict__ bias,
                 void* __restrict__ Cv,
                 int N, int K,
                 long sA, long sB, long sC, float scale) {
    __shared__ unsigned short lA[128 * 64];
    __shared__ unsigned short lB[128 * 64];
    const int t = threadIdx.x;
    const int w = t >> 6, l = t & 63;
    const int bm = blockIdx.y, bn = blockIdx.x, bz = blockIdx.z;
    const unsigned short* Ab = A + (size_t)bz * sA + (size_t)(bm * 128) * K;
    const unsigned short* Bb = Bt + (size_t)bz * sB + (size_t)(bn * 128) * K;

    const int wr = w >> 1, wc = w & 1;          // wave -> 64x64 quadrant
    f32x4 acc[4][4] = {};

    const int srow = t >> 3;
    const int scol = (t & 7) * 8;

    for (int k0 = 0; k0 < K; k0 += 64) {
        #pragma unroll
        for (int i = 0; i < 4; i++) {
            gl_lds16(Ab + (size_t)(i * 32 + srow) * K + (k0 + scol),
                     lA + i * 2048 + w * 512);
            gl_lds16(Bb + (size_t)(i * 32 + srow) * K + (k0 + scol),
                     lB + i * 2048 + w * 512);
        }
        __syncthreads();
        #pragma unroll
        for (int kk = 0; kk < 2; kk++) {
            const int kb = kk * 32 + (l >> 4) * 8;
            bf16x8 af[4], bfv[4];
            #pragma unroll
            for (int mi = 0; mi < 4; mi++)
                af[mi] = *(const bf16x8*)(lA + (wr * 64 + mi * 16 + (l & 15)) * 64 + kb);
            #pragma unroll
            for (int ni = 0; ni < 4; ni++)
                bfv[ni] = *(const bf16x8*)(lB + (wc * 64 + ni * 16 + (l & 15)) * 64 + kb);
            #pragma unroll
            for (int mi = 0; mi < 4; mi++)
                #pragma unroll
                for (int ni = 0; ni < 4; ni++)
                    acc[mi][ni] = __builtin_amdgcn_mfma_f32_16x16x32_bf16(
                        af[mi], bfv[ni], acc[mi][ni], 0, 0, 0);
        }
        __syncthreads();
    }

    const int cn0 = bn * 128 + wc * 64 + (l & 15);
    const int cm0 = bm * 128 + wr * 64 + ((l >> 4) << 2);
    #pragma unroll
    for (int ni = 0; ni < 4; ni++) {
        const int n = cn0 + ni * 16;
        const float bvs = bias ? bias[n] : 0.0f;
        #pragma unroll
        for (int mi = 0; mi < 4; mi++) {
            #pragma unroll
            for (int r = 0; r < 4; r++) {
                const int m = cm0 + mi * 16 + r;
                const size_t off = (size_t)bz * sC + (size_t)m * N + n;
                const float v = acc[mi][ni][r] * scale + bvs;
                if (EPI == 0) {
                    ((unsigned short*)Cv)[off] = f2bf(v);
                } else if (EPI == 1) {
                    ((unsigned short*)Cv)[off] = f2bf(fmaxf(v, 0.0f));
                } else {
                    float* cp = (float*)Cv + off;
                    *cp += v;
                }
            }
        }
    }
}

// ---------------- masked softmax, rows local to the group -------------------
__global__ __launch_bounds__(256)
void softmax_kernel(unsigned short* __restrict__ sc, const float* __restrict__ mbg) {
    const int row = blockIdx.x * 4 + (threadIdx.x >> 6);   // row in [0, G*NS)
    const int l = threadIdx.x & 63;
    const int b = row >> 10;                               // batch local to group
    unsigned short* rp = sc + (size_t)row * NS;
    const float* mrow = mbg + (size_t)b * NS;
    float v[16];
    float mx = -3.4e38f;
    #pragma unroll
    for (int j = 0; j < 2; j++) {
        u16x8 u = *(const u16x8*)(rp + j * 512 + l * 8);
        f32x4 m0 = *(const f32x4*)(mrow + j * 512 + l * 8);
        f32x4 m1 = *(const f32x4*)(mrow + j * 512 + l * 8 + 4);
        #pragma unroll
        for (int i = 0; i < 8; i++) {
            const float s = bf2f(u[i]) + (i < 4 ? m0[i] : m1[i - 4]);
            v[j * 8 + i] = s;
            mx = fmaxf(mx, s);
        }
    }
    #pragma unroll
    for (int off = 32; off >= 1; off >>= 1) mx = fmaxf(mx, __shfl_xor(mx, off));
    float sum = 0.f;
    #pragma unroll
    for (int i = 0; i < 16; i++) { v[i] = __expf(v[i] - mx); sum += v[i]; }
    #pragma unroll
    for (int off = 32; off >= 1; off >>= 1) sum += __shfl_xor(sum, off);
    const float inv = 1.0f / sum;
    #pragma unroll
    for (int j = 0; j < 2; j++) {
        u16x8 o;
        #pragma unroll
        for (int i = 0; i < 8; i++) o[i] = f2bf(v[j * 8 + i] * inv);
        *(u16x8*)(rp + j * 512 + l * 8) = o;
    }
}

// ---------------- masked mean pool (group-local batches) --------------------
__global__ void pool_kernel(const unsigned short* __restrict__ ln,
                            const int* __restrict__ tokg,
                            float* __restrict__ pooledg) {
    const int b = blockIdx.y;                  // local batch
    const int d = blockIdx.x * 256 + threadIdx.x;
    float s = 0.f, cnt = 0.f;
    for (int i = 0; i < NS; i++) {
        const int tk = tokg[b * NS + i];
        if (tk != 0) { s += bf2f(ln[((size_t)b * NS + i) * ND + d]); cnt += 1.0f; }
    }
    pooledg[(size_t)b * ND + d] = s / fmaxf(cnt, 1.0f);
}

// ---------------- classifier -> FLOAT32 output ------------------------------
__global__ void cls_kernel(const float* __restrict__ pooled, const float* __restrict__ wc,
                           const float* __restrict__ bc, float* __restrict__ out) {
    const int b = blockIdx.x;
    const int l = threadIdx.x;                  // 64 threads
    float a[6] = {0, 0, 0, 0, 0, 0};
    for (int d = l; d < ND; d += 64) {
        const float p = pooled[b * ND + d];
        #pragma unroll
        for (int c = 0; c < 6; c++) a[c] += p * wc[d * 6 + c];
    }
    #pragma unroll
    for (int c = 0; c < 6; c++) {
        #pragma unroll
        for (int off = 32; off >= 1; off >>= 1) a[c] += __shfl_xor(a[c], off);
    }
    if (l == 0) {
        #pragma unroll
        for (int c = 0; c < 6; c++) out[b * 6 + c] = a[c] + bc[c];
    }
}

__global__ void zero_out_kernel(float* out, int nel) {
    const int i = blockIdx.x * 256 + threadIdx.x;
    if (i < nel) out[i] = 0.0f;
}

// ---------------------------------------------------------------------------
extern "C" void kernel_launch(void* const* d_in, const int* in_sizes, int n_in,
                              void* d_out, int out_size, void* d_ws, size_t ws_size,
                              hipStream_t stream) {
    const int*   tok  = (const int*)d_in[0];
    const float* emb  = (const float*)d_in[1];
    const float* pos  = (const float*)d_in[2];
    const float* ln1w = (const float*)d_in[3];
    const float* ln1b = (const float*)d_in[4];
    const float* ln2w = (const float*)d_in[5];
    const float* ln2b = (const float*)d_in[6];
    const float* wq   = (const float*)d_in[7];
    const float* bq   = (const float*)d_in[8];
    const float* wk   = (const float*)d_in[9];
    const float* bk   = (const float*)d_in[10];
    const float* wv   = (const float*)d_in[11];
    const float* bv   = (const float*)d_in[12];
    const float* w1   = (const float*)d_in[13];
    const float* b1   = (const float*)d_in[14];
    const float* w2   = (const float*)d_in[15];
    const float* b2   = (const float*)d_in[16];
    const float* lnfw = (const float*)d_in[17];
    const float* lnfb = (const float*)d_in[18];
    const float* wcw  = (const float*)d_in[19];
    const float* bcb  = (const float*)d_in[20];
    float* out = (float*)d_out;                 // FLOAT32 output (ref dtype)

    // ---- fixed workspace carve-up (~134 MB) ----
    size_t off = 0;
    auto carve = [&](size_t bytes) -> char* {
        char* p = (char*)d_ws + off;
        off += (bytes + 255) & ~(size_t)255;
        return p;
    };
    float* x = (float*)carve((size_t)NM * ND * 4);                 // fp32 residual
    unsigned short* wqT = (unsigned short*)carve((size_t)NL * ND * ND * 2);
    unsigned short* wkT = (unsigned short*)carve((size_t)NL * ND * ND * 2);
    unsigned short* wvT = (unsigned short*)carve((size_t)NL * ND * ND * 2);
    unsigned short* w1T = (unsigned short*)carve((size_t)NL * ND * NH * 2);
    unsigned short* w2T = (unsigned short*)carve((size_t)NL * NH * ND * 2);
    float* mb     = (float*)carve((size_t)NM * 4);
    float* pooled = (float*)carve((size_t)NB * ND * 4);

    // ---- adaptive group size: per-group pool = G * 8.4 MiB ----
    int G = 32;
    while (G >= 1) {
        const size_t pool = (size_t)G * (4u * NS * ND * 2u + (size_t)NS * NS * 2u);
        if (off + pool <= ws_size) break;
        G >>= 1;
    }
    if (G < 1) {   // workspace too small even for G=1: clean fail (diagnostic)
        zero_out_kernel<<<(out_size + 255) / 256, 256, 0, stream>>>(out, out_size);
        return;
    }
    const int MG = G * NS;                       // rows per group
    unsigned short* n  = (unsigned short*)carve((size_t)MG * ND * 2);
    unsigned short* q  = (unsigned short*)carve((size_t)MG * ND * 2);
    unsigned short* k  = (unsigned short*)carve((size_t)MG * ND * 2);
    unsigned short* v  = (unsigned short*)carve((size_t)MG * ND * 2);
    unsigned short* sc = (unsigned short*)carve((size_t)G * NS * NS * 2);
    unsigned short* vt = n;                      // alias: n dead between QKV and LN2
    unsigned short* h  = q;                      // alias: q+k contiguous = [MG][NH]

    // ---- prepass ----
    embed_kernel<<<NM, 192, 0, stream>>>(tok, emb, pos, x);
    mask_kernel<<<NM / 256, 256, 0, stream>>>(tok, mb);
    wt_kernel<<<dim3(12, 12, NL), 256, 0, stream>>>(wq, wqT, ND, ND);
    wt_kernel<<<dim3(12, 12, NL), 256, 0, stream>>>(wk, wkT, ND, ND);
    wt_kernel<<<dim3(12, 12, NL), 256, 0, stream>>>(wv, wvT, ND, ND);
    wt_kernel<<<dim3(24, 12, NL), 256, 0, stream>>>(w1, w1T, ND, NH);
    wt_kernel<<<dim3(12, 24, NL), 256, 0, stream>>>(w2, w2T, NH, ND);

    const float iscale = 1.0f / sqrtf((float)ND);
    const int NGroups = NB / G;
    for (int l = 0; l < NL; l++) {
        for (int g = 0; g < NGroups; g++) {
            const size_t rowoff = (size_t)g * MG;
            float* xg = x + rowoff * ND;
            ln_kernel<<<MG / 4, 256, 0, stream>>>(xg, ln1w + l * ND, ln1b + l * ND, n);
            gemm_kernel<0><<<dim3(6, MG / 128, 1), 256, 0, stream>>>(
                n, wqT + (size_t)l * ND * ND, bq + l * ND, q, ND, ND, 0, 0, 0, 1.0f);
            gemm_kernel<0><<<dim3(6, MG / 128, 1), 256, 0, stream>>>(
                n, wkT + (size_t)l * ND * ND, bk + l * ND, k, ND, ND, 0, 0, 0, 1.0f);
            gemm_kernel<0><<<dim3(6, MG / 128, 1), 256, 0, stream>>>(
                n, wvT + (size_t)l * ND * ND, bv + l * ND, v, ND, ND, 0, 0, 0, 1.0f);
            tv_kernel<<<dim3(16, 12, G), 256, 0, stream>>>(v, vt);
            gemm_kernel<0><<<dim3(8, 8, G), 256, 0, stream>>>(
                q, k, nullptr, sc, NS, ND,
                (long)NS * ND, (long)NS * ND, (long)NS * NS, iscale);
            softmax_kernel<<<MG / 4, 256, 0, stream>>>(sc, mb + rowoff);
            gemm_kernel<2><<<dim3(6, 8, G), 256, 0, stream>>>(
                sc, vt, nullptr, xg, ND, NS,
                (long)NS * NS, (long)ND * NS, (long)NS * ND, 1.0f);
            ln_kernel<<<MG / 4, 256, 0, stream>>>(xg, ln2w + l * ND, ln2b + l * ND, n);
            gemm_kernel<1><<<dim3(12, MG / 128, 1), 256, 0, stream>>>(
                n, w1T + (size_t)l * ND * NH, b1 + l * NH, h, NH, ND, 0, 0, 0, 1.0f);
            gemm_kernel<2><<<dim3(6, MG / 128, 1), 256, 0, stream>>>(
                h, w2T + (size_t)l * ND * NH, b2 + l * ND, xg, ND, NH, 0, 0, 0, 1.0f);
        }
    }
    for (int g = 0; g < NGroups; g++) {
        const size_t rowoff = (size_t)g * MG;
        ln_kernel<<<MG / 4, 256, 0, stream>>>(x + rowoff * ND, lnfw, lnfb, n);
        pool_kernel<<<dim3(3, G), 256, 0, stream>>>(n, tok + rowoff, pooled + (size_t)g * G * ND);
    }
    cls_kernel<<<NB, 64, 0, stream>>>(pooled, wcw, bcb, out);
}

// Round 4
// 3728.664 us; speedup vs baseline: 1.2005x; 1.2005x over previous
//
#include <hip/hip_runtime.h>
#include <hip/hip_bf16.h>

// ---------------------------------------------------------------------------
// Transformer encoder fwd: B=32, S=1024, D=768, L=4, H=1536, C=6
// bf16 MFMA GEMMs, fp32 residual. Output FLOAT32.
// R4: pool 2-stage (was 278us latency-bound), V^T via operand-swapped GEMM
// (tv_kernel removed), fused QK projection (lda/ldb strided GEMM), mask
// fused into softmax. GEMM inner loop unchanged (m97 structure).
// ---------------------------------------------------------------------------

typedef float f32x4 __attribute__((ext_vector_type(4)));
typedef unsigned short u16x4 __attribute__((ext_vector_type(4)));
typedef unsigned short u16x8 __attribute__((ext_vector_type(8)));
typedef int   i32x4 __attribute__((ext_vector_type(4)));
typedef __bf16 bf16x8 __attribute__((ext_vector_type(8)));

#define NB  32
#define NS  1024
#define ND  768
#define NH  1536
#define NL  4
#define NM  (NB * NS)   // 32768 rows total

__device__ __forceinline__ unsigned short f2bf(float f) {
    unsigned u = __builtin_bit_cast(unsigned, f);
    unsigned r = (u + 0x7FFFu + ((u >> 16) & 1u)) >> 16;   // RNE
    return (unsigned short)r;
}
__device__ __forceinline__ float bf2f(unsigned short h) {
    return __builtin_bit_cast(float, (unsigned)h << 16);
}

__device__ __forceinline__ void gl_lds16(const void* g, void* l) {
    __builtin_amdgcn_global_load_lds(
        (const __attribute__((address_space(1))) unsigned int*)g,
        (__attribute__((address_space(3))) unsigned int*)l, 16, 0, 0);
}

// ---------------- embedding ------------------------------------------------
__global__ void embed_kernel(const int* __restrict__ tok,
                             const float* __restrict__ emb,
                             const float* __restrict__ pos,
                             float* __restrict__ x) {
    const int row = blockIdx.x;
    const int c = threadIdx.x;                 // 192 threads, one float4 each
    const int tk = tok[row];
    const int s = row & (NS - 1);
    f32x4 e = *(const f32x4*)(emb + (size_t)tk * ND + c * 4);
    f32x4 p = *(const f32x4*)(pos + (size_t)s * ND + c * 4);
    f32x4 r = e + p;
    *(f32x4*)(x + (size_t)row * ND + c * 4) = r;
}

// ---------------- weight fp32 [R][C] -> bf16 transposed [C][R], z-strided ---
__global__ __launch_bounds__(256)
void wt_kernel(const float* __restrict__ in, unsigned short* __restrict__ out,
               int R, int Cc, size_t ozs) {
    __shared__ float ls[64][65];
    const int t = threadIdx.x;
    const size_t zi = (size_t)blockIdx.z * R * Cc;
    const size_t zo = (size_t)blockIdx.z * ozs;
    const int r0 = blockIdx.y * 64, c0 = blockIdx.x * 64;
    #pragma unroll
    for (int i = 0; i < 4; i++) {
        const int r = i * 16 + (t >> 4);
        const int c = (t & 15) * 4;
        f32x4 v = *(const f32x4*)(in + zi + (size_t)(r0 + r) * Cc + c0 + c);
        ls[r][c] = v[0]; ls[r][c + 1] = v[1]; ls[r][c + 2] = v[2]; ls[r][c + 3] = v[3];
    }
    __syncthreads();
    #pragma unroll
    for (int i = 0; i < 2; i++) {
        const int c = i * 32 + (t >> 3);
        const int r = (t & 7) * 8;
        u16x8 o;
        #pragma unroll
        for (int j = 0; j < 8; j++) o[j] = f2bf(ls[r + j][c]);
        *(u16x8*)(out + zo + (size_t)(c0 + c) * R + r0 + r) = o;
    }
}

// ---------------- concat bias [bq|bk] per layer -----------------------------
__global__ void bcat_kernel(const float* __restrict__ bq, const float* __restrict__ bk,
                            float* __restrict__ bqk) {
    const int i = blockIdx.x * 256 + threadIdx.x;       // NL*1536
    const int l = i / NH, j = i % NH;
    bqk[i] = (j < ND) ? bq[l * ND + j] : bk[l * ND + j - ND];
}

// ---------------- LayerNorm fp32 in -> bf16 out, one wave per row -----------
__global__ __launch_bounds__(256)
void ln_kernel(const float* __restrict__ x, const float* __restrict__ g,
               const float* __restrict__ bta, unsigned short* __restrict__ out) {
    const int row = blockIdx.x * 4 + (threadIdx.x >> 6);
    const int l = threadIdx.x & 63;
    const float* xr = x + (size_t)row * ND;
    f32x4 vv[3];
    float s = 0.f, ss = 0.f;
    #pragma unroll
    for (int j = 0; j < 3; j++) {
        vv[j] = *(const f32x4*)(xr + (j * 64 + l) * 4);
        #pragma unroll
        for (int i = 0; i < 4; i++) { s += vv[j][i]; ss += vv[j][i] * vv[j][i]; }
    }
    #pragma unroll
    for (int off = 32; off >= 1; off >>= 1) {
        s += __shfl_xor(s, off); ss += __shfl_xor(ss, off);
    }
    const float mean = s * (1.0f / ND);
    const float var = ss * (1.0f / ND) - mean * mean;
    const float rstd = rsqrtf(var + 1e-5f);
    #pragma unroll
    for (int j = 0; j < 3; j++) {
        const int c = (j * 64 + l) * 4;
        f32x4 gv = *(const f32x4*)(g + c);
        f32x4 bv = *(const f32x4*)(bta + c);
        u16x4 o;
        #pragma unroll
        for (int i = 0; i < 4; i++) o[i] = f2bf((vv[j][i] - mean) * rstd * gv[i] + bv[i]);
        *(u16x4*)(out + (size_t)row * ND + c) = o;
    }
}

// ---------------- GEMM: C[M,N] = A[M,K](bf16) @ Bt[N,K](bf16)^T -------------
// 128x128 tile, BK=64, 4 waves, 16x16x32 MFMA, global_load_lds staging.
// lda/ldb: row strides of A / Bt (elements). C row stride = N.
// EPI: 0 = scale+bias -> bf16; 1 = relu(bias+v) -> bf16; 2 = fp32 C += v
// BROW: bias indexed by output ROW m (for the V^T-producing GEMM).
template<int EPI, int BROW>
__global__ __launch_bounds__(256)
void gemm_kernel(const unsigned short* __restrict__ A,
                 const unsigned short* __restrict__ Bt,
                 const float* __restrict__ bias,
                 void* __restrict__ Cv,
                 int N, int K, int lda, int ldb,
                 long sA, long sB, long sC, float scale) {
    __shared__ unsigned short lA[128 * 64];
    __shared__ unsigned short lB[128 * 64];
    const int t = threadIdx.x;
    const int w = t >> 6, l = t & 63;
    const int bm = blockIdx.y, bn = blockIdx.x, bz = blockIdx.z;
    const unsigned short* Ab = A + (size_t)bz * sA + (size_t)(bm * 128) * lda;
    const unsigned short* Bb = Bt + (size_t)bz * sB + (size_t)(bn * 128) * ldb;

    const int wr = w >> 1, wc = w & 1;          // wave -> 64x64 quadrant
    f32x4 acc[4][4] = {};

    const int srow = t >> 3;
    const int scol = (t & 7) * 8;

    for (int k0 = 0; k0 < K; k0 += 64) {
        #pragma unroll
        for (int i = 0; i < 4; i++) {
            gl_lds16(Ab + (size_t)(i * 32 + srow) * lda + (k0 + scol),
                     lA + i * 2048 + w * 512);
            gl_lds16(Bb + (size_t)(i * 32 + srow) * ldb + (k0 + scol),
                     lB + i * 2048 + w * 512);
        }
        __syncthreads();
        #pragma unroll
        for (int kk = 0; kk < 2; kk++) {
            const int kb = kk * 32 + (l >> 4) * 8;
            bf16x8 af[4], bfv[4];
            #pragma unroll
            for (int mi = 0; mi < 4; mi++)
                af[mi] = *(const bf16x8*)(lA + (wr * 64 + mi * 16 + (l & 15)) * 64 + kb);
            #pragma unroll
            for (int ni = 0; ni < 4; ni++)
                bfv[ni] = *(const bf16x8*)(lB + (wc * 64 + ni * 16 + (l & 15)) * 64 + kb);
            #pragma unroll
            for (int mi = 0; mi < 4; mi++)
                #pragma unroll
                for (int ni = 0; ni < 4; ni++)
                    acc[mi][ni] = __builtin_amdgcn_mfma_f32_16x16x32_bf16(
                        af[mi], bfv[ni], acc[mi][ni], 0, 0, 0);
        }
        __syncthreads();
    }

    const int cn0 = bn * 128 + wc * 64 + (l & 15);
    const int cm0 = bm * 128 + wr * 64 + ((l >> 4) << 2);
    #pragma unroll
    for (int ni = 0; ni < 4; ni++) {
        const int n = cn0 + ni * 16;
        const float bcol = (!BROW && bias) ? bias[n] : 0.0f;
        #pragma unroll
        for (int mi = 0; mi < 4; mi++) {
            f32x4 brow = {0, 0, 0, 0};
            if (BROW) brow = *(const f32x4*)(bias + cm0 + mi * 16);
            #pragma unroll
            for (int r = 0; r < 4; r++) {
                const int m = cm0 + mi * 16 + r;
                const size_t off = (size_t)bz * sC + (size_t)m * N + n;
                const float v = acc[mi][ni][r] * scale + (BROW ? brow[r] : bcol);
                if (EPI == 0) {
                    ((unsigned short*)Cv)[off] = f2bf(v);
                } else if (EPI == 1) {
                    ((unsigned short*)Cv)[off] = f2bf(fmaxf(v, 0.0f));
                } else {
                    float* cp = (float*)Cv + off;
                    *cp += v;
                }
            }
        }
    }
}

// ---------------- masked softmax (mask from tokens), group-local ------------
__global__ __launch_bounds__(256)
void softmax_kernel(unsigned short* __restrict__ sc, const int* __restrict__ tokg) {
    const int row = blockIdx.x * 4 + (threadIdx.x >> 6);   // row in [0, G*NS)
    const int l = threadIdx.x & 63;
    const int b = row >> 10;                               // batch local to group
    unsigned short* rp = sc + (size_t)row * NS;
    const int* trow = tokg + (size_t)b * NS;
    float v[16];
    float mx = -3.4e38f;
    #pragma unroll
    for (int j = 0; j < 2; j++) {
        u16x8 u = *(const u16x8*)(rp + j * 512 + l * 8);
        i32x4 t0 = *(const i32x4*)(trow + j * 512 + l * 8);
        i32x4 t1 = *(const i32x4*)(trow + j * 512 + l * 8 + 4);
        #pragma unroll
        for (int i = 0; i < 8; i++) {
            const int tk = (i < 4) ? t0[i] : t1[i - 4];
            const float s = (tk == 0) ? -__builtin_inff() : bf2f(u[i]);
            v[j * 8 + i] = s;
            mx = fmaxf(mx, s);
        }
    }
    #pragma unroll
    for (int off = 32; off >= 1; off >>= 1) mx = fmaxf(mx, __shfl_xor(mx, off));
    float sum = 0.f;
    #pragma unroll
    for (int i = 0; i < 16; i++) { v[i] = __expf(v[i] - mx); sum += v[i]; }
    #pragma unroll
    for (int off = 32; off >= 1; off >>= 1) sum += __shfl_xor(sum, off);
    const float inv = 1.0f / sum;
    #pragma unroll
    for (int j = 0; j < 2; j++) {
        u16x8 o;
        #pragma unroll
        for (int i = 0; i < 8; i++) o[i] = f2bf(v[j * 8 + i] * inv);
        *(u16x8*)(rp + j * 512 + l * 8) = o;
    }
}

// ---------------- pool stage 1: partial masked sums over 128-row chunks -----
__global__ __launch_bounds__(256)
void pool1_kernel(const unsigned short* __restrict__ ln,
                  const int* __restrict__ tokg,
                  float* __restrict__ part, float* __restrict__ cnts,
                  int gbase) {                     // gbase: global batch offset
    const int d = blockIdx.x * 256 + threadIdx.x;  // 0..767
    const int b = blockIdx.y;                      // local batch
    const int z = blockIdx.z;                      // seq chunk 0..7
    float s = 0.f, cnt = 0.f;
    const int i0 = z * 128;
    for (int i = i0; i < i0 + 128; i++) {
        const int tk = tokg[b * NS + i];
        if (tk != 0) { s += bf2f(ln[((size_t)b * NS + i) * ND + d]); cnt += 1.0f; }
    }
    part[((size_t)z * NB + (gbase + b)) * ND + d] = s;
    if (d == 0) cnts[z * NB + (gbase + b)] = cnt;
}

// ---------------- pool stage 2: finalize -----------------------------------
__global__ __launch_bounds__(256)
void pool2_kernel(const float* __restrict__ part, const float* __restrict__ cnts,
                  float* __restrict__ pooled) {
    const int d = blockIdx.x * 256 + threadIdx.x;
    const int b = blockIdx.y;                      // global batch
    float s = 0.f, cnt = 0.f;
    #pragma unroll
    for (int z = 0; z < 8; z++) {
        s += part[((size_t)z * NB + b) * ND + d];
        cnt += cnts[z * NB + b];
    }
    pooled[(size_t)b * ND + d] = s / fmaxf(cnt, 1.0f);
}

// ---------------- classifier -> FLOAT32 output ------------------------------
__global__ void cls_kernel(const float* __restrict__ pooled, const float* __restrict__ wc,
                           const float* __restrict__ bc, float* __restrict__ out) {
    const int b = blockIdx.x;
    const int l = threadIdx.x;                  // 64 threads
    float a[6] = {0, 0, 0, 0, 0, 0};
    for (int d = l; d < ND; d += 64) {
        const float p = pooled[b * ND + d];
        #pragma unroll
        for (int c = 0; c < 6; c++) a[c] += p * wc[d * 6 + c];
    }
    #pragma unroll
    for (int c = 0; c < 6; c++) {
        #pragma unroll
        for (int off = 32; off >= 1; off >>= 1) a[c] += __shfl_xor(a[c], off);
    }
    if (l == 0) {
        #pragma unroll
        for (int c = 0; c < 6; c++) out[b * 6 + c] = a[c] + bc[c];
    }
}

__global__ void zero_out_kernel(float* out, int nel) {
    const int i = blockIdx.x * 256 + threadIdx.x;
    if (i < nel) out[i] = 0.0f;
}

// ---------------------------------------------------------------------------
extern "C" void kernel_launch(void* const* d_in, const int* in_sizes, int n_in,
                              void* d_out, int out_size, void* d_ws, size_t ws_size,
                              hipStream_t stream) {
    const int*   tok  = (const int*)d_in[0];
    const float* emb  = (const float*)d_in[1];
    const float* pos  = (const float*)d_in[2];
    const float* ln1w = (const float*)d_in[3];
    const float* ln1b = (const float*)d_in[4];
    const float* ln2w = (const float*)d_in[5];
    const float* ln2b = (const float*)d_in[6];
    const float* wq   = (const float*)d_in[7];
    const float* bq   = (const float*)d_in[8];
    const float* wk   = (const float*)d_in[9];
    const float* bk   = (const float*)d_in[10];
    const float* wv   = (const float*)d_in[11];
    const float* bv   = (const float*)d_in[12];
    const float* w1   = (const float*)d_in[13];
    const float* b1   = (const float*)d_in[14];
    const float* w2   = (const float*)d_in[15];
    const float* b2   = (const float*)d_in[16];
    const float* lnfw = (const float*)d_in[17];
    const float* lnfb = (const float*)d_in[18];
    const float* wcw  = (const float*)d_in[19];
    const float* bcb  = (const float*)d_in[20];
    float* out = (float*)d_out;                 // FLOAT32 output (ref dtype)

    // ---- fixed workspace carve-up (~135 MB) ----
    size_t off = 0;
    auto carve = [&](size_t bytes) -> char* {
        char* p = (char*)d_ws + off;
        off += (bytes + 255) & ~(size_t)255;
        return p;
    };
    float* x = (float*)carve((size_t)NM * ND * 4);                 // fp32 residual
    unsigned short* wqkT = (unsigned short*)carve((size_t)NL * NH * ND * 2); // [l][1536][768]
    unsigned short* wvT  = (unsigned short*)carve((size_t)NL * ND * ND * 2);
    unsigned short* w1T  = (unsigned short*)carve((size_t)NL * ND * NH * 2);
    unsigned short* w2T  = (unsigned short*)carve((size_t)NL * NH * ND * 2);
    float* bqk    = (float*)carve((size_t)NL * NH * 4);
    float* part   = (float*)carve((size_t)8 * NB * ND * 4);
    float* cnts   = (float*)carve((size_t)8 * NB * 4);
    float* pooled = (float*)carve((size_t)NB * ND * 4);

    // ---- adaptive group size: per-batch pool = 8 MiB ----
    int G = 32;
    while (G >= 1) {
        const size_t pool = (size_t)G *
            ((size_t)NS * ND * 2      // n
           + (size_t)NS * NH * 2      // qk (aliased by h)
           + (size_t)NS * ND * 2      // vt
           + (size_t)NS * NS * 2);    // sc
        if (off + pool <= ws_size) break;
        G >>= 1;
    }
    if (G < 1) {   // workspace too small even for G=1: clean fail (diagnostic)
        zero_out_kernel<<<(out_size + 255) / 256, 256, 0, stream>>>(out, out_size);
        return;
    }
    const int MG = G * NS;                       // rows per group
    unsigned short* n  = (unsigned short*)carve((size_t)MG * ND * 2);
    unsigned short* qk = (unsigned short*)carve((size_t)MG * NH * 2);
    unsigned short* vt = (unsigned short*)carve((size_t)MG * ND * 2); // [b][768][1024]
    unsigned short* sc = (unsigned short*)carve((size_t)G * NS * NS * 2);
    unsigned short* h  = qk;                     // alias: qk dead after scores

    // ---- prepass ----
    embed_kernel<<<NM, 192, 0, stream>>>(tok, emb, pos, x);
    wt_kernel<<<dim3(12, 12, NL), 256, 0, stream>>>(wq, wqkT,            ND, ND, (size_t)NH * ND);
    wt_kernel<<<dim3(12, 12, NL), 256, 0, stream>>>(wk, wqkT + ND * ND,  ND, ND, (size_t)NH * ND);
    wt_kernel<<<dim3(12, 12, NL), 256, 0, stream>>>(wv, wvT,             ND, ND, (size_t)ND * ND);
    wt_kernel<<<dim3(24, 12, NL), 256, 0, stream>>>(w1, w1T,             ND, NH, (size_t)ND * NH);
    wt_kernel<<<dim3(12, 24, NL), 256, 0, stream>>>(w2, w2T,             NH, ND, (size_t)NH * ND);
    bcat_kernel<<<NL * NH / 256, 256, 0, stream>>>(bq, bk, bqk);

    const float iscale = 1.0f / sqrtf((float)ND);
    const int NGroups = NB / G;
    for (int l = 0; l < NL; l++) {
        for (int g = 0; g < NGroups; g++) {
            const size_t rowoff = (size_t)g * MG;
            float* xg = x + rowoff * ND;
            ln_kernel<<<MG / 4, 256, 0, stream>>>(xg, ln1w + l * ND, ln1b + l * ND, n);
            // QK fused: qk[MG][1536] = n @ [wq|wk]^T + [bq|bk]
            gemm_kernel<0, 0><<<dim3(12, MG / 128, 1), 256, 0, stream>>>(
                n, wqkT + (size_t)l * NH * ND, bqk + l * NH, qk,
                NH, ND, ND, ND, 0, 0, 0, 1.0f);
            // V^T direct: vt[b][d][s] = wvT[d][:] . n[b][s][:] + bv[d]
            gemm_kernel<0, 1><<<dim3(8, 6, G), 256, 0, stream>>>(
                wvT + (size_t)l * ND * ND, n, bv + l * ND, vt,
                NS, ND, ND, ND, 0, (long)NS * ND, (long)ND * NS, 1.0f);
            // scores = q @ k^T * iscale   (q,k strided views of qk)
            gemm_kernel<0, 0><<<dim3(8, 8, G), 256, 0, stream>>>(
                qk, qk + ND, nullptr, sc,
                NS, ND, NH, NH, (long)NS * NH, (long)NS * NH, (long)NS * NS, iscale);
            softmax_kernel<<<MG / 4, 256, 0, stream>>>(sc, tok + rowoff);
            // x += attn @ V   (Bt = vt)
            gemm_kernel<2, 0><<<dim3(6, 8, G), 256, 0, stream>>>(
                sc, vt, nullptr, xg,
                ND, NS, NS, NS, (long)NS * NS, (long)ND * NS, (long)NS * ND, 1.0f);
            ln_kernel<<<MG / 4, 256, 0, stream>>>(xg, ln2w + l * ND, ln2b + l * ND, n);
            gemm_kernel<1, 0><<<dim3(12, MG / 128, 1), 256, 0, stream>>>(
                n, w1T + (size_t)l * ND * NH, b1 + l * NH, h,
                NH, ND, ND, ND, 0, 0, 0, 1.0f);
            gemm_kernel<2, 0><<<dim3(6, MG / 128, 1), 256, 0, stream>>>(
                h, w2T + (size_t)l * ND * NH, b2 + l * ND, xg,
                ND, NH, NH, NH, 0, 0, 0, 1.0f);
        }
    }
    for (int g = 0; g < NGroups; g++) {
        const size_t rowoff = (size_t)g * MG;
        ln_kernel<<<MG / 4, 256, 0, stream>>>(x + rowoff * ND, lnfw, lnfb, n);
        pool1_kernel<<<dim3(3, G, 8), 256, 0, stream>>>(n, tok + rowoff, part, cnts, g * G);
    }
    pool2_kernel<<<dim3(3, NB), 256, 0, stream>>>(part, cnts, pooled);
    cls_kernel<<<NB, 64, 0, stream>>>(pooled, wcw, bcb, out);
}

// Round 5
// 3036.159 us; speedup vs baseline: 1.4743x; 1.2281x over previous
//
#include <hip/hip_runtime.h>
#include <hip/hip_bf16.h>

// ---------------------------------------------------------------------------
// Transformer encoder fwd: B=32, S=1024, D=768, L=4, H=1536, C=6
// bf16 MFMA GEMMs, fp32 residual. Output FLOAT32.
// R5: all GEMMs moved to the 256x256 8-phase template (T2 LDS XOR-swizzle +
// T3/T4 counted vmcnt + T5 setprio + T1 XCD swizzle). Raw s_barrier only —
// no __syncthreads in the K-loop (it would drain vmcnt). 512 thr, 8 waves,
// 128 KiB LDS, BK=64, per-wave 128x64 output, 64 MFMA/K-tile/wave.
// ---------------------------------------------------------------------------

typedef float f32x4 __attribute__((ext_vector_type(4)));
typedef unsigned short u16x4 __attribute__((ext_vector_type(4)));
typedef unsigned short u16x8 __attribute__((ext_vector_type(8)));
typedef int   i32x4 __attribute__((ext_vector_type(4)));
typedef __bf16 bf16x8 __attribute__((ext_vector_type(8)));

#define NB  32
#define NS  1024
#define ND  768
#define NH  1536
#define NL  4
#define NM  (NB * NS)   // 32768 rows total

__device__ __forceinline__ unsigned short f2bf(float f) {
    unsigned u = __builtin_bit_cast(unsigned, f);
    unsigned r = (u + 0x7FFFu + ((u >> 16) & 1u)) >> 16;   // RNE
    return (unsigned short)r;
}
__device__ __forceinline__ float bf2f(unsigned short h) {
    return __builtin_bit_cast(float, (unsigned)h << 16);
}

__device__ __forceinline__ void gl_lds16(const void* g, void* l) {
    __builtin_amdgcn_global_load_lds(
        (const __attribute__((address_space(1))) unsigned int*)g,
        (__attribute__((address_space(3))) unsigned int*)l, 16, 0, 0);
}

// ---------------- embedding ------------------------------------------------
__global__ void embed_kernel(const int* __restrict__ tok,
                             const float* __restrict__ emb,
                             const float* __restrict__ pos,
                             float* __restrict__ x) {
    const int row = blockIdx.x;
    const int c = threadIdx.x;                 // 192 threads, one float4 each
    const int tk = tok[row];
    const int s = row & (NS - 1);
    f32x4 e = *(const f32x4*)(emb + (size_t)tk * ND + c * 4);
    f32x4 p = *(const f32x4*)(pos + (size_t)s * ND + c * 4);
    f32x4 r = e + p;
    *(f32x4*)(x + (size_t)row * ND + c * 4) = r;
}

// ---------------- weight fp32 [R][C] -> bf16 transposed [C][R], z-strided ---
__global__ __launch_bounds__(256)
void wt_kernel(const float* __restrict__ in, unsigned short* __restrict__ out,
               int R, int Cc, size_t ozs) {
    __shared__ float ls[64][65];
    const int t = threadIdx.x;
    const size_t zi = (size_t)blockIdx.z * R * Cc;
    const size_t zo = (size_t)blockIdx.z * ozs;
    const int r0 = blockIdx.y * 64, c0 = blockIdx.x * 64;
    #pragma unroll
    for (int i = 0; i < 4; i++) {
        const int r = i * 16 + (t >> 4);
        const int c = (t & 15) * 4;
        f32x4 v = *(const f32x4*)(in + zi + (size_t)(r0 + r) * Cc + c0 + c);
        ls[r][c] = v[0]; ls[r][c + 1] = v[1]; ls[r][c + 2] = v[2]; ls[r][c + 3] = v[3];
    }
    __syncthreads();
    #pragma unroll
    for (int i = 0; i < 2; i++) {
        const int c = i * 32 + (t >> 3);
        const int r = (t & 7) * 8;
        u16x8 o;
        #pragma unroll
        for (int j = 0; j < 8; j++) o[j] = f2bf(ls[r + j][c]);
        *(u16x8*)(out + zo + (size_t)(c0 + c) * R + r0 + r) = o;
    }
}

// ---------------- concat bias [bq|bk] per layer -----------------------------
__global__ void bcat_kernel(const float* __restrict__ bq, const float* __restrict__ bk,
                            float* __restrict__ bqk) {
    const int i = blockIdx.x * 256 + threadIdx.x;       // NL*1536
    const int l = i / NH, j = i % NH;
    bqk[i] = (j < ND) ? bq[l * ND + j] : bk[l * ND + j - ND];
}

// ---------------- LayerNorm fp32 in -> bf16 out, one wave per row -----------
__global__ __launch_bounds__(256)
void ln_kernel(const float* __restrict__ x, const float* __restrict__ g,
               const float* __restrict__ bta, unsigned short* __restrict__ out) {
    const int row = blockIdx.x * 4 + (threadIdx.x >> 6);
    const int l = threadIdx.x & 63;
    const float* xr = x + (size_t)row * ND;
    f32x4 vv[3];
    float s = 0.f, ss = 0.f;
    #pragma unroll
    for (int j = 0; j < 3; j++) {
        vv[j] = *(const f32x4*)(xr + (j * 64 + l) * 4);
        #pragma unroll
        for (int i = 0; i < 4; i++) { s += vv[j][i]; ss += vv[j][i] * vv[j][i]; }
    }
    #pragma unroll
    for (int off = 32; off >= 1; off >>= 1) {
        s += __shfl_xor(s, off); ss += __shfl_xor(ss, off);
    }
    const float mean = s * (1.0f / ND);
    const float var = ss * (1.0f / ND) - mean * mean;
    const float rstd = rsqrtf(var + 1e-5f);
    #pragma unroll
    for (int j = 0; j < 3; j++) {
        const int c = (j * 64 + l) * 4;
        f32x4 gv = *(const f32x4*)(g + c);
        f32x4 bv = *(const f32x4*)(bta + c);
        u16x4 o;
        #pragma unroll
        for (int i = 0; i < 4; i++) o[i] = f2bf((vv[j][i] - mean) * rstd * gv[i] + bv[i]);
        *(u16x4*)(out + (size_t)row * ND + c) = o;
    }
}

// ---------------- GEMM 256x256, 8-phase: C = A[M,K] @ Bt[N,K]^T -------------
// 512 threads = 8 waves (2M x 4N), per-wave 128x64 out, BK=64, dbuf LDS 128K.
// LDS swizzle: byte ^= (row&7)<<4 on BOTH pre-swizzled gl_lds source and
// ds_read address (involution; 16B-chunk aligned). Staging stream per tile t:
// p0:A(t+1).h0  p1:A(t+1).h1  p2:B(t+2).h0  p3:B(t+2).h1 ; vmcnt(4) at p3.
// B(t+2) lands in the currently-read buffer, but B reads all happen at p0 and
// the stores are issued >=2 barriers later -> race-free.
// EPI: 0 = scale+bias -> bf16; 1 = relu(bias+v) -> bf16; 2 = fp32 C += v
// BROW: bias indexed by output ROW m (for the V^T-producing GEMM).
template<int EPI, int BROW>
__global__ __launch_bounds__(512, 2)
void gemm256_kernel(const unsigned short* __restrict__ A,
                    const unsigned short* __restrict__ Bt,
                    const float* __restrict__ bias,
                    void* __restrict__ Cv,
                    int N, int K, int lda, int ldb,
                    long sA, long sB, long sC, float scale, int doswz) {
    __shared__ unsigned short lds[65536];      // 128 KiB
    const int tid = threadIdx.x;
    const int wid = tid >> 6, l = tid & 63;
    const int wr = wid >> 2, wc = wid & 3;     // wave -> 2x4 grid
    const int fr = l & 15, fq = l >> 4;

    int bn = blockIdx.x, bm = blockIdx.y;
    const int bz = blockIdx.z;
    if (doswz) {                               // T1: XCD-aware remap (nwg%8==0)
        const int X = gridDim.x;
        const int nwg = X * gridDim.y;
        const int flat = bm * X + bn;
        const int s = (flat & 7) * (nwg >> 3) + (flat >> 3);
        bn = s % X; bm = s / X;
    }

    const unsigned short* Ab = A + (size_t)bz * sA + (size_t)(bm * 256) * lda;
    const unsigned short* Bb = Bt + (size_t)bz * sB + (size_t)(bn * 256) * ldb;

    // staging geometry: thread covers row (tid>>3), 8 elems; source col
    // pre-swizzled so the LINEAR gl_lds write lands swizzled data.
    const int srow = tid >> 3;                           // 0..63
    const int scol = ((tid & 7) ^ (srow & 7)) * 8;       // elems
    const unsigned ldst = (unsigned)wid * 1024u;         // wave base (bytes)

    auto stageA = [&](int kt, int h) {
        const unsigned base = (unsigned)(kt & 1) * 65536u + (unsigned)h * 16384u;
        #pragma unroll
        for (int li = 0; li < 2; li++)
            gl_lds16(Ab + (size_t)(h * 128 + li * 64 + srow) * lda + (kt * 64 + scol),
                     (char*)lds + base + (unsigned)li * 8192u + ldst);
    };
    auto stageB = [&](int kt, int h) {
        const unsigned base = (unsigned)(kt & 1) * 65536u + 32768u + (unsigned)h * 16384u;
        #pragma unroll
        for (int li = 0; li < 2; li++)
            gl_lds16(Bb + (size_t)(h * 128 + li * 64 + srow) * ldb + (kt * 64 + scol),
                     (char*)lds + base + (unsigned)li * 8192u + ldst);
    };
    auto ldaf = [&](int buf, int mi, int kk) -> bf16x8 {
        const unsigned r = (unsigned)(mi * 16 + fr);
        unsigned byt = r * 128u + (unsigned)kk * 64u + (unsigned)fq * 16u;
        byt ^= (r & 7u) << 4;
        return *(const bf16x8*)((const char*)lds +
            (unsigned)buf * 65536u + (unsigned)wr * 16384u + byt);
    };
    auto ldbf = [&](int buf, int ni, int kk) -> bf16x8 {
        const unsigned r = (unsigned)((wc & 1) * 64 + ni * 16 + fr);
        unsigned byt = r * 128u + (unsigned)kk * 64u + (unsigned)fq * 16u;
        byt ^= (r & 7u) << 4;
        return *(const bf16x8*)((const char*)lds +
            (unsigned)buf * 65536u + 32768u + (unsigned)(wc >> 1) * 16384u + byt);
    };

    const int NT = K >> 6;
    f32x4 acc[8][4] = {};

    // ---- prologue: B(0), A(0), B(1); wait so B(0)+A(0) resident -----------
    stageB(0, 0); stageB(0, 1); stageA(0, 0); stageA(0, 1);
    if (NT > 1) {
        stageB(1, 0); stageB(1, 1);
        asm volatile("s_waitcnt vmcnt(4)" ::: "memory");
    } else {
        asm volatile("s_waitcnt vmcnt(0)" ::: "memory");
    }
    __builtin_amdgcn_s_barrier();
    __builtin_amdgcn_sched_barrier(0);

    for (int t = 0; t < NT; ++t) {
        const int cur = t & 1;
        bf16x8 bfr[8];                         // B-frags: [ni*2+kk], live all 4 phases
        #pragma unroll
        for (int ni = 0; ni < 4; ni++) {
            bfr[ni * 2 + 0] = ldbf(cur, ni, 0);
            bfr[ni * 2 + 1] = ldbf(cur, ni, 1);
        }
        #pragma unroll
        for (int p = 0; p < 4; p++) {
            bf16x8 a0 = ldaf(cur, 2 * p,     0);
            bf16x8 a1 = ldaf(cur, 2 * p,     1);
            bf16x8 a2 = ldaf(cur, 2 * p + 1, 0);
            bf16x8 a3 = ldaf(cur, 2 * p + 1, 1);
            if (p < 2) { if (t + 1 < NT) stageA(t + 1, p); }
            else       { if (t + 2 < NT) stageB(t + 2, p - 2); }
            if (p == 3) {                      // tile boundary: counted drain
                if (t + 2 < NT) asm volatile("s_waitcnt vmcnt(4)" ::: "memory");
                else            asm volatile("s_waitcnt vmcnt(0)" ::: "memory");
            }
            __builtin_amdgcn_s_barrier();
            asm volatile("s_waitcnt lgkmcnt(0)" ::: "memory");
            __builtin_amdgcn_sched_barrier(0);
            __builtin_amdgcn_s_setprio(1);
            #pragma unroll
            for (int ni = 0; ni < 4; ni++) {
                acc[2 * p][ni] = __builtin_amdgcn_mfma_f32_16x16x32_bf16(
                    a0, bfr[ni * 2 + 0], acc[2 * p][ni], 0, 0, 0);
                acc[2 * p][ni] = __builtin_amdgcn_mfma_f32_16x16x32_bf16(
                    a1, bfr[ni * 2 + 1], acc[2 * p][ni], 0, 0, 0);
                acc[2 * p + 1][ni] = __builtin_amdgcn_mfma_f32_16x16x32_bf16(
                    a2, bfr[ni * 2 + 0], acc[2 * p + 1][ni], 0, 0, 0);
                acc[2 * p + 1][ni] = __builtin_amdgcn_mfma_f32_16x16x32_bf16(
                    a3, bfr[ni * 2 + 1], acc[2 * p + 1][ni], 0, 0, 0);
            }
            __builtin_amdgcn_s_setprio(0);
            __builtin_amdgcn_sched_barrier(0);
            __builtin_amdgcn_s_barrier();
            __builtin_amdgcn_sched_barrier(0);
        }
    }

    // ---- epilogue (registers only; no barrier needed) ----------------------
    const int cn0 = bn * 256 + wc * 64 + fr;
    const int cm0 = bm * 256 + wr * 128 + fq * 4;
    #pragma unroll
    for (int ni = 0; ni < 4; ni++) {
        const int nn = cn0 + ni * 16;
        const float bcol = (!BROW && bias) ? bias[nn] : 0.0f;
        #pragma unroll
        for (int mi = 0; mi < 8; mi++) {
            f32x4 brow = {0, 0, 0, 0};
            if (BROW) brow = *(const f32x4*)(bias + cm0 + mi * 16);
            #pragma unroll
            for (int r = 0; r < 4; r++) {
                const int m = cm0 + mi * 16 + r;
                const size_t offc = (size_t)bz * sC + (size_t)m * N + nn;
                const float v = acc[mi][ni][r] * scale + (BROW ? brow[r] : bcol);
                if (EPI == 0)      ((unsigned short*)Cv)[offc] = f2bf(v);
                else if (EPI == 1) ((unsigned short*)Cv)[offc] = f2bf(fmaxf(v, 0.0f));
                else               ((float*)Cv)[offc] += v;
            }
        }
    }
}

// ---------------- masked softmax (mask from tokens), group-local ------------
__global__ __launch_bounds__(256)
void softmax_kernel(unsigned short* __restrict__ sc, const int* __restrict__ tokg) {
    const int row = blockIdx.x * 4 + (threadIdx.x >> 6);   // row in [0, G*NS)
    const int l = threadIdx.x & 63;
    const int b = row >> 10;                               // batch local to group
    unsigned short* rp = sc + (size_t)row * NS;
    const int* trow = tokg + (size_t)b * NS;
    float v[16];
    float mx = -3.4e38f;
    #pragma unroll
    for (int j = 0; j < 2; j++) {
        u16x8 u = *(const u16x8*)(rp + j * 512 + l * 8);
        i32x4 t0 = *(const i32x4*)(trow + j * 512 + l * 8);
        i32x4 t1 = *(const i32x4*)(trow + j * 512 + l * 8 + 4);
        #pragma unroll
        for (int i = 0; i < 8; i++) {
            const int tk = (i < 4) ? t0[i] : t1[i - 4];
            const float s = (tk == 0) ? -__builtin_inff() : bf2f(u[i]);
            v[j * 8 + i] = s;
            mx = fmaxf(mx, s);
        }
    }
    #pragma unroll
    for (int off = 32; off >= 1; off >>= 1) mx = fmaxf(mx, __shfl_xor(mx, off));
    float sum = 0.f;
    #pragma unroll
    for (int i = 0; i < 16; i++) { v[i] = __expf(v[i] - mx); sum += v[i]; }
    #pragma unroll
    for (int off = 32; off >= 1; off >>= 1) sum += __shfl_xor(sum, off);
    const float inv = 1.0f / sum;
    #pragma unroll
    for (int j = 0; j < 2; j++) {
        u16x8 o;
        #pragma unroll
        for (int i = 0; i < 8; i++) o[i] = f2bf(v[j * 8 + i] * inv);
        *(u16x8*)(rp + j * 512 + l * 8) = o;
    }
}

// ---------------- pool stage 1: partial masked sums over 128-row chunks -----
__global__ __launch_bounds__(256)
void pool1_kernel(const unsigned short* __restrict__ ln,
                  const int* __restrict__ tokg,
                  float* __restrict__ part, float* __restrict__ cnts,
                  int gbase) {                     // gbase: global batch offset
    const int d = blockIdx.x * 256 + threadIdx.x;  // 0..767
    const int b = blockIdx.y;                      // local batch
    const int z = blockIdx.z;                      // seq chunk 0..7
    float s = 0.f, cnt = 0.f;
    const int i0 = z * 128;
    for (int i = i0; i < i0 + 128; i++) {
        const int tk = tokg[b * NS + i];
        if (tk != 0) { s += bf2f(ln[((size_t)b * NS + i) * ND + d]); cnt += 1.0f; }
    }
    part[((size_t)z * NB + (gbase + b)) * ND + d] = s;
    if (d == 0) cnts[z * NB + (gbase + b)] = cnt;
}

// ---------------- pool stage 2: finalize -----------------------------------
__global__ __launch_bounds__(256)
void pool2_kernel(const float* __restrict__ part, const float* __restrict__ cnts,
                  float* __restrict__ pooled) {
    const int d = blockIdx.x * 256 + threadIdx.x;
    const int b = blockIdx.y;                      // global batch
    float s = 0.f, cnt = 0.f;
    #pragma unroll
    for (int z = 0; z < 8; z++) {
        s += part[((size_t)z * NB + b) * ND + d];
        cnt += cnts[z * NB + b];
    }
    pooled[(size_t)b * ND + d] = s / fmaxf(cnt, 1.0f);
}

// ---------------- classifier -> FLOAT32 output ------------------------------
__global__ void cls_kernel(const float* __restrict__ pooled, const float* __restrict__ wc,
                           const float* __restrict__ bc, float* __restrict__ out) {
    const int b = blockIdx.x;
    const int l = threadIdx.x;                  // 64 threads
    float a[6] = {0, 0, 0, 0, 0, 0};
    for (int d = l; d < ND; d += 64) {
        const float p = pooled[b * ND + d];
        #pragma unroll
        for (int c = 0; c < 6; c++) a[c] += p * wc[d * 6 + c];
    }
    #pragma unroll
    for (int c = 0; c < 6; c++) {
        #pragma unroll
        for (int off = 32; off >= 1; off >>= 1) a[c] += __shfl_xor(a[c], off);
    }
    if (l == 0) {
        #pragma unroll
        for (int c = 0; c < 6; c++) out[b * 6 + c] = a[c] + bc[c];
    }
}

__global__ void zero_out_kernel(float* out, int nel) {
    const int i = blockIdx.x * 256 + threadIdx.x;
    if (i < nel) out[i] = 0.0f;
}

// ---------------------------------------------------------------------------
extern "C" void kernel_launch(void* const* d_in, const int* in_sizes, int n_in,
                              void* d_out, int out_size, void* d_ws, size_t ws_size,
                              hipStream_t stream) {
    const int*   tok  = (const int*)d_in[0];
    const float* emb  = (const float*)d_in[1];
    const float* pos  = (const float*)d_in[2];
    const float* ln1w = (const float*)d_in[3];
    const float* ln1b = (const float*)d_in[4];
    const float* ln2w = (const float*)d_in[5];
    const float* ln2b = (const float*)d_in[6];
    const float* wq   = (const float*)d_in[7];
    const float* bq   = (const float*)d_in[8];
    const float* wk   = (const float*)d_in[9];
    const float* bk   = (const float*)d_in[10];
    const float* wv   = (const float*)d_in[11];
    const float* bv   = (const float*)d_in[12];
    const float* w1   = (const float*)d_in[13];
    const float* b1   = (const float*)d_in[14];
    const float* w2   = (const float*)d_in[15];
    const float* b2   = (const float*)d_in[16];
    const float* lnfw = (const float*)d_in[17];
    const float* lnfb = (const float*)d_in[18];
    const float* wcw  = (const float*)d_in[19];
    const float* bcb  = (const float*)d_in[20];
    float* out = (float*)d_out;                 // FLOAT32 output (ref dtype)

    // ---- fixed workspace carve-up (~135 MB) ----
    size_t off = 0;
    auto carve = [&](size_t bytes) -> char* {
        char* p = (char*)d_ws + off;
        off += (bytes + 255) & ~(size_t)255;
        return p;
    };
    float* x = (float*)carve((size_t)NM * ND * 4);                 // fp32 residual
    unsigned short* wqkT = (unsigned short*)carve((size_t)NL * NH * ND * 2); // [l][1536][768]
    unsigned short* wvT  = (unsigned short*)carve((size_t)NL * ND * ND * 2);
    unsigned short* w1T  = (unsigned short*)carve((size_t)NL * ND * NH * 2);
    unsigned short* w2T  = (unsigned short*)carve((size_t)NL * NH * ND * 2);
    float* bqk    = (float*)carve((size_t)NL * NH * 4);
    float* part   = (float*)carve((size_t)8 * NB * ND * 4);
    float* cnts   = (float*)carve((size_t)8 * NB * 4);
    float* pooled = (float*)carve((size_t)NB * ND * 4);

    // ---- adaptive group size ----
    int G = 32;
    while (G >= 1) {
        const size_t pool = (size_t)G *
            ((size_t)NS * ND * 2      // n
           + (size_t)NS * NH * 2      // qk (aliased by h)
           + (size_t)NS * ND * 2      // vt
           + (size_t)NS * NS * 2);    // sc
        if (off + pool <= ws_size) break;
        G >>= 1;
    }
    if (G < 1) {
        zero_out_kernel<<<(out_size + 255) / 256, 256, 0, stream>>>(out, out_size);
        return;
    }
    const int MG = G * NS;                       // rows per group
    unsigned short* n  = (unsigned short*)carve((size_t)MG * ND * 2);
    unsigned short* qk = (unsigned short*)carve((size_t)MG * NH * 2);
    unsigned short* vt = (unsigned short*)carve((size_t)MG * ND * 2); // [b][768][1024]
    unsigned short* sc = (unsigned short*)carve((size_t)G * NS * NS * 2);
    unsigned short* h  = qk;                     // alias: qk dead after scores

    // ---- prepass ----
    embed_kernel<<<NM, 192, 0, stream>>>(tok, emb, pos, x);
    wt_kernel<<<dim3(12, 12, NL), 256, 0, stream>>>(wq, wqkT,            ND, ND, (size_t)NH * ND);
    wt_kernel<<<dim3(12, 12, NL), 256, 0, stream>>>(wk, wqkT + ND * ND,  ND, ND, (size_t)NH * ND);
    wt_kernel<<<dim3(12, 12, NL), 256, 0, stream>>>(wv, wvT,             ND, ND, (size_t)ND * ND);
    wt_kernel<<<dim3(24, 12, NL), 256, 0, stream>>>(w1, w1T,             ND, NH, (size_t)ND * NH);
    wt_kernel<<<dim3(12, 24, NL), 256, 0, stream>>>(w2, w2T,             NH, ND, (size_t)NH * ND);
    bcat_kernel<<<NL * NH / 256, 256, 0, stream>>>(bq, bk, bqk);

    const float iscale = 1.0f / sqrtf((float)ND);
    const int NGroups = NB / G;
    const int MT = MG / 256;                     // row tiles of the big GEMMs (=4G)
    const int swz6 = ((6 * MT) % 8 == 0) ? 1 : 0;
    const int swz3 = ((3 * MT) % 8 == 0) ? 1 : 0;
    for (int l = 0; l < NL; l++) {
        for (int g = 0; g < NGroups; g++) {
            const size_t rowoff = (size_t)g * MG;
            float* xg = x + rowoff * ND;
            ln_kernel<<<MG / 4, 256, 0, stream>>>(xg, ln1w + l * ND, ln1b + l * ND, n);
            // QK fused: qk[MG][1536] = n @ [wq|wk]^T + [bq|bk]
            gemm256_kernel<0, 0><<<dim3(6, MT, 1), 512, 0, stream>>>(
                n, wqkT + (size_t)l * NH * ND, bqk + l * NH, qk,
                NH, ND, ND, ND, 0, 0, 0, 1.0f, swz6);
            // V^T direct: vt[b][d][s] = wvT[d][:] . n[b][s][:] + bv[d]
            gemm256_kernel<0, 1><<<dim3(4, 3, G), 512, 0, stream>>>(
                wvT + (size_t)l * ND * ND, n, bv + l * ND, vt,
                NS, ND, ND, ND, 0, (long)NS * ND, (long)ND * NS, 1.0f, 0);
            // scores = q @ k^T * iscale   (q,k strided views of qk)
            gemm256_kernel<0, 0><<<dim3(4, 4, G), 512, 0, stream>>>(
                qk, qk + ND, nullptr, sc,
                NS, ND, NH, NH, (long)NS * NH, (long)NS * NH, (long)NS * NS, iscale, 0);
            softmax_kernel<<<MG / 4, 256, 0, stream>>>(sc, tok + rowoff);
            // x += attn @ V   (Bt = vt)
            gemm256_kernel<2, 0><<<dim3(3, 4, G), 512, 0, stream>>>(
                sc, vt, nullptr, xg,
                ND, NS, NS, NS, (long)NS * NS, (long)ND * NS, (long)NS * ND, 1.0f, 0);
            ln_kernel<<<MG / 4, 256, 0, stream>>>(xg, ln2w + l * ND, ln2b + l * ND, n);
            gemm256_kernel<1, 0><<<dim3(6, MT, 1), 512, 0, stream>>>(
                n, w1T + (size_t)l * ND * NH, b1 + l * NH, h,
                NH, ND, ND, ND, 0, 0, 0, 1.0f, swz6);
            gemm256_kernel<2, 0><<<dim3(3, MT, 1), 512, 0, stream>>>(
                h, w2T + (size_t)l * ND * NH, b2 + l * ND, xg,
                ND, NH, NH, NH, 0, 0, 0, 1.0f, swz3);
        }
    }
    for (int g = 0; g < NGroups; g++) {
        const size_t rowoff = (size_t)g * MG;
        ln_kernel<<<MG / 4, 256, 0, stream>>>(x + rowoff * ND, lnfw, lnfb, n);
        pool1_kernel<<<dim3(3, G, 8), 256, 0, stream>>>(n, tok + rowoff, part, cnts, g * G);
    }
    pool2_kernel<<<dim3(3, NB), 256, 0, stream>>>(part, cnts, pooled);
    cls_kernel<<<NB, 64, 0, stream>>>(pooled, wcw, bcb, out);
}